// Round 6
// baseline (266.066 us; speedup 1.0000x reference)
//
#include <hip/hip_runtime.h>
#include <cstddef>

#define NB 64
#define LL 512
#define HH 256
#define HD 128
#define NG 512
#define TI 16

typedef _Float16 half_t;
typedef _Float16 half8 __attribute__((ext_vector_type(8)));
typedef _Float16 half4 __attribute__((ext_vector_type(4)));
typedef float f32x4 __attribute__((ext_vector_type(4)));

#define MFMA16(a, b, c) __builtin_amdgcn_mfma_f32_16x16x32_f16((a), (b), (c), 0, 0, 0)

// LDS pitches (<=2-way bank aliasing, free on CDNA4)
#define FP 264   // sFeatb pitch (f16)
#define XP 518   // sXG pitch (f32)
#define HBP 136  // sHb pitch (f16)
#define EP 17    // sE inner pitch (f32)

// fast gates: v_rcp_f32 (~1 ulp) instead of full-precision divide.
__device__ __forceinline__ float sigm(float x)  { return __builtin_amdgcn_rcpf(1.0f + __expf(-x)); }
__device__ __forceinline__ float tanhf_(float x){ return 2.0f * __builtin_amdgcn_rcpf(1.0f + __expf(-2.0f * x)) - 1.0f; }

// 16-lane (DPP-row) sum on the VALU pipe: no DS ops.
template <int CTRL>
__device__ __forceinline__ float dppadd(float x) {
    int v = __builtin_amdgcn_update_dpp(0, __float_as_int(x), CTRL, 0xF, 0xF, true);
    return x + __int_as_float(v);
}
__device__ __forceinline__ float row16_sum(float x) {
    x = dppadd<0xB1>(x);    // quad_perm [1,0,3,2]
    x = dppadd<0x4E>(x);    // quad_perm [2,3,0,1]
    x = dppadd<0x141>(x);   // row_half_mirror
    x = dppadd<0x140>(x);   // row_mirror
    return x;
}

// Barrier with LDS visibility but NO vmcnt drain: keeps the block's output
// stores in flight across the whole t-loop (__syncthreads would drain them).
__device__ __forceinline__ void barrier_lgkm() {
    asm volatile("s_waitcnt lgkmcnt(0)" ::: "memory");
    __builtin_amdgcn_s_barrier();
    asm volatile("" ::: "memory");
}

// ---- prep: cast weights to f16, bsum = b_ih + b_hh ----
__global__ void prep_weights(const float* __restrict__ Wih, const float* __restrict__ Whh,
                             const float* __restrict__ bih, const float* __restrict__ bhh,
                             half_t* __restrict__ WihH, half_t* __restrict__ WhhH,
                             float* __restrict__ bsum)
{
    const int idx = blockIdx.x * 256 + threadIdx.x;
    if (idx < NG * HH) WihH[idx] = (half_t)Wih[idx];
    if (idx < NG * HD) WhhH[idx] = (half_t)Whh[idx];
    if (idx < NG)      bsum[idx] = bih[idx] + bhh[idx];
}

// launch_bounds(512,4): 128 unified VGPR/AGPR per lane. (512,6) spilled the
// fragment set to scratch (round-2: +850 MB HBM). Do not raise waves/EU.
__global__ __launch_bounds__(512, 4) void span_lstm_mfma(
    const float* __restrict__ feats, const half_t* __restrict__ WihH,
    const half_t* __restrict__ WhhH, const float* __restrict__ bsum,
    const float* __restrict__ W_tri, const float* __restrict__ b_tri,
    const int* __restrict__ lens, float* __restrict__ out)
{
    __shared__ __align__(16) half_t sFeatb[20 * FP];
    __shared__ __align__(16) float  sXG[20 * XP];
    __shared__ __align__(16) half_t sHb[2][16 * HBP];
    __shared__ __align__(16) float  sE[4][16 * EP];   // [ts][s*EP + wv*2 + tag]

    float* sVal = (float*)sFeatb;   // [16][4][2]; live only after the t-loop

    const int tid = threadIdx.x;
    const int b  = blockIdx.x >> 5;
    const int i0 = (blockIdx.x & 31) * TI;
    const int lens_b = lens[b];

    float* ob = out + ((size_t)b * LL + i0) * (LL * 2);
    const f32x4 zz = {0.f, 0.f, 0.f, 0.f};

    // ---- dead-block fast path: whole slice is zeros ----
    if (i0 >= lens_b) {
        #pragma unroll
        for (int k = 0; k < 8; ++k)
            __builtin_nontemporal_store(zz, (f32x4*)(ob + (size_t)(k * 512 + tid) * 4));
        return;
    }

    const int lane = tid & 63, wv = tid >> 6;   // 8 waves
    const int lm = lane & 15;                   // m / n within 16-tile (DPP row-local)
    const int lq = lane >> 4;                   // quad
    const int jw = wv * 16;                     // this wave's hidden-column slice

    // ---- stage feats window (20 rows) as f16 (pre-store phase: normal sync ok) ----
    for (int idx = tid; idx < 20 * 64; idx += 512) {
        const int p  = idx >> 6;
        const int k4 = (idx & 63) << 2;
        const int gp = i0 + p;
        float4 v = make_float4(0.f, 0.f, 0.f, 0.f);
        if (gp < LL) v = *(const float4*)(feats + ((size_t)b * LL + gp) * HH + k4);
        half4 hv = {(half_t)v.x, (half_t)v.y, (half_t)v.z, (half_t)v.w};
        *(half4*)(&sFeatb[p * FP + k4]) = hv;
    }
    __syncthreads();

    // ---- phase 1: wave computes XG only for ITS gate columns (4 ta x 16 cols) ----
    {
        half8 afr[2][8];
        #pragma unroll
        for (int mt = 0; mt < 2; ++mt)
            #pragma unroll
            for (int kf = 0; kf < 8; ++kf)
                afr[mt][kf] = *(const half8*)(&sFeatb[(16 * mt + lm) * FP + kf * 32 + lq * 8]);

        #pragma unroll
        for (int ta = 0; ta < 4; ++ta) {
            const int gb = ta * HD + jw;
            const float bs = bsum[gb + lm];
            f32x4 acc0 = {0.f, 0.f, 0.f, 0.f}, acc1 = {0.f, 0.f, 0.f, 0.f};
            #pragma unroll
            for (int kf = 0; kf < 8; ++kf) {
                const half8 bfr = *(const half8*)(WihH + (size_t)(gb + lm) * HH + kf * 32 + lq * 8);
                acc0 = MFMA16(afr[0][kf], bfr, acc0);
                acc1 = MFMA16(afr[1][kf], bfr, acc1);
            }
            #pragma unroll
            for (int r = 0; r < 4; ++r)
                sXG[(lq * 4 + r) * XP + gb + lm] = acc0[r] + bs;
            if (lq == 0) {
                #pragma unroll
                for (int r = 0; r < 4; ++r)
                    sXG[(16 + r) * XP + gb + lm] = acc1[r] + bs;
            }
        }
    }

    // ---- remaining global LOADS, all issued before any output store ----
    half8 bf2[4][4];
    #pragma unroll
    for (int ta = 0; ta < 4; ++ta)
        #pragma unroll
        for (int kf = 0; kf < 4; ++kf)
            bf2[ta][kf] = *(const half8*)(WhhH + (size_t)(ta * HD + jw + lm) * HD
                                          + kf * 32 + lq * 8);
    const float wt0 = W_tri[jw + lm];
    const float wt1 = W_tri[HD + jw + lm];
    const float bt0 = b_tri[0], bt1 = b_tri[1];

    // Pin loads resident BEFORE the stores: compiler's waitcnts land here, so no
    // later wait ever forces the (newer, in-order-retired) stores to drain.
    asm volatile("" :: "v"(wt0), "v"(wt1), "v"(bt0), "v"(bt1));
    #pragma unroll
    for (int ta = 0; ta < 4; ++ta)
        #pragma unroll
        for (int kf = 0; kf < 4; ++kf)
            asm volatile("" :: "v"(bf2[ta][kf]));

    // ---- EARLY bulk zero-fill (nontemporal, fire-and-forget): every chunk of
    // this block's 64 KB slice that cannot hold an emission value. These stores
    // stay in flight across the whole t-loop (raw barriers below never drain
    // vmcnt), fixing the ~1 TB/s drain-serialized write floor of rounds 0-5.
    #pragma unroll
    for (int k = 0; k < 8; ++k) {
        const int cg = k * 512 + tid;
        const int es = cg >> 8, c = cg & 255;
        const int i  = i0 + es;
        bool mixed = false;
        if (i < lens_b) {
            const int chi = ((i + 3 < LL) ? (i + 3) : (LL - 1)) >> 1;
            mixed = (c >= (i >> 1)) && (c <= chi);
        }
        if (!mixed)
            __builtin_nontemporal_store(zz, (f32x4*)(ob + (size_t)cg * 4));
    }

    float cc4[4] = {0.f, 0.f, 0.f, 0.f};
    float hhA[4][4];   // all 4 steps' h in f32 regs -> emission outside the loop

    // ---- recurrence: minimal barrier-locked body; raw barriers (no vmcnt drain) ----
    #pragma unroll
    for (int t = 0; t < 4; ++t) {
        float accg[4][4];
        if (t > 0) {
            half8 ah[4];
            #pragma unroll
            for (int kf = 0; kf < 4; ++kf)
                ah[kf] = *(const half8*)(&sHb[(t - 1) & 1][lm * HBP + kf * 32 + lq * 8]);
            #pragma unroll
            for (int ta = 0; ta < 4; ++ta) {
                f32x4 a = {0.f, 0.f, 0.f, 0.f};
                #pragma unroll
                for (int kf = 0; kf < 4; ++kf)
                    a = MFMA16(ah[kf], bf2[ta][kf], a);
                #pragma unroll
                for (int r = 0; r < 4; ++r) accg[ta][r] = a[r];
            }
        } else {
            #pragma unroll
            for (int ta = 0; ta < 4; ++ta)
                #pragma unroll
                for (int r = 0; r < 4; ++r) accg[ta][r] = 0.f;
        }
        #pragma unroll
        for (int ta = 0; ta < 4; ++ta)
            #pragma unroll
            for (int r = 0; r < 4; ++r)
                accg[ta][r] += sXG[(lq * 4 + r + t) * XP + ta * HD + jw + lm];

        #pragma unroll
        for (int r = 0; r < 4; ++r) {
            const float ig = sigm(accg[0][r]);
            const float fg = sigm(accg[1][r]);
            const float gg = tanhf_(accg[2][r]);
            const float og = sigm(accg[3][r]);
            cc4[r] = fg * cc4[r] + ig * gg;
            hhA[t][r] = og * tanhf_(cc4[r]);
        }

        if (t < 3) {
            #pragma unroll
            for (int r = 0; r < 4; ++r)
                sHb[t & 1][(lq * 4 + r) * HBP + jw + lm] = (half_t)hhA[t][r];
            barrier_lgkm();
        }
    }

    // ---- emission: DPP row-sums, f32-exact, outside the barrier cadence ----
    #pragma unroll
    for (int ts = 0; ts < 4; ++ts)
        #pragma unroll
        for (int r = 0; r < 4; ++r) {
            float e0 = row16_sum(hhA[ts][r] * wt0);
            float e1 = row16_sum(hhA[ts][r] * wt1);
            if (lm == 0) {
                float2 v = make_float2(e0, e1);
                *(float2*)&sE[ts][(lq * 4 + r) * EP + wv * 2] = v;
            }
        }
    barrier_lgkm();   // sE visible

    // ---- finalize: value per (span-row es, width w, tag) into sVal ----
    if (tid < 128) {
        const int es = tid & 15, tag = (tid >> 4) & 1, w = (tid >> 5) + 1;
        const int i = i0 + es;
        const int rem = lens_b - i;
        float e = 0.f;
        if (rem > 0 && (i + w - 1) < LL) {
            const int ts = (rem < w ? rem : w) - 1;   // selected step (0-based)
            e = tag ? bt1 : bt0;
            #pragma unroll
            for (int k = 0; k < 8; ++k) e += sE[ts][es * EP + k * 2 + tag];
        }
        sVal[(es * 4 + (w - 1)) * 2 + tag] = e;
    }
    barrier_lgkm();   // sVal visible

    // ---- tail: only the <=3 mixed chunks per live row (complement of the
    // early zero set -- every output address written exactly once) ----
    if (tid < 48) {
        const int es = tid & 15, m = tid >> 4;   // m in 0..2
        const int i = i0 + es;
        if (i < lens_b) {
            const int chi = ((i + 3 < LL) ? (i + 3) : (LL - 1)) >> 1;
            const int c = (i >> 1) + m;
            if (c <= chi) {
                const int j0 = 2 * c;
                f32x4 v = {0.f, 0.f, 0.f, 0.f};
                const int w0 = j0 - i + 1;
                if ((unsigned)(w0 - 1) < 4u) {
                    v.x = sVal[(es * 4 + (w0 - 1)) * 2 + 0];
                    v.y = sVal[(es * 4 + (w0 - 1)) * 2 + 1];
                }
                const int w1 = w0 + 1;
                if ((unsigned)(w1 - 1) < 4u) {
                    v.z = sVal[(es * 4 + (w1 - 1)) * 2 + 0];
                    v.w = sVal[(es * 4 + (w1 - 1)) * 2 + 1];
                }
                *(f32x4*)(ob + ((size_t)es * 256 + c) * 4) = v;
            }
        }
    }
}

extern "C" void kernel_launch(void* const* d_in, const int* in_sizes, int n_in,
                              void* d_out, int out_size, void* d_ws, size_t ws_size,
                              hipStream_t stream)
{
    const float* feats = (const float*)d_in[0];
    const float* W_ih  = (const float*)d_in[1];
    const float* W_hh  = (const float*)d_in[2];
    const float* b_ih  = (const float*)d_in[3];
    const float* b_hh  = (const float*)d_in[4];
    const float* W_tri = (const float*)d_in[5];
    const float* b_tri = (const float*)d_in[6];
    const int*   lens  = (const int*)d_in[7];
    float* out = (float*)d_out;

    // ws layout: WihH (256 KB) | WhhH (128 KB) | bsum (2 KB)
    half_t* WihH = (half_t*)d_ws;
    half_t* WhhH = WihH + (size_t)NG * HH;
    float*  bsum = (float*)(WhhH + (size_t)NG * HD);

    prep_weights<<<(NG * HH + 255) / 256, 256, 0, stream>>>(W_ih, W_hh, b_ih, b_hh,
                                                            WihH, WhhH, bsum);
    span_lstm_mfma<<<NB * (LL / TI), 512, 0, stream>>>(feats, WihH, WhhH, bsum,
                                                       W_tri, b_tri, lens, out);
}

// Round 7
// 258.060 us; speedup vs baseline: 1.0310x; 1.0310x over previous
//
#include <hip/hip_runtime.h>
#include <cstddef>

#define NB 64
#define LL 512
#define HH 256
#define HD 128
#define NG 512
#define TI 16

typedef _Float16 half_t;
typedef _Float16 half8 __attribute__((ext_vector_type(8)));
typedef _Float16 half4 __attribute__((ext_vector_type(4)));
typedef float f32x4 __attribute__((ext_vector_type(4)));

#define MFMA16(a, b, c) __builtin_amdgcn_mfma_f32_16x16x32_f16((a), (b), (c), 0, 0, 0)

// LDS pitches (<=2-way bank aliasing, free on CDNA4)
#define FP 264   // sFeatb pitch (f16)
#define XP 518   // sXG pitch (f32)
#define HBP 136  // sHb pitch (f16)
#define EP 17    // sE inner pitch (f32)

// fast gates: v_rcp_f32 (~1 ulp) instead of full-precision divide.
__device__ __forceinline__ float sigm(float x)  { return __builtin_amdgcn_rcpf(1.0f + __expf(-x)); }
__device__ __forceinline__ float tanhf_(float x){ return 2.0f * __builtin_amdgcn_rcpf(1.0f + __expf(-2.0f * x)) - 1.0f; }

// 16-lane (DPP-row) sum on the VALU pipe: no DS ops.
template <int CTRL>
__device__ __forceinline__ float dppadd(float x) {
    int v = __builtin_amdgcn_update_dpp(0, __float_as_int(x), CTRL, 0xF, 0xF, true);
    return x + __int_as_float(v);
}
__device__ __forceinline__ float row16_sum(float x) {
    x = dppadd<0xB1>(x);    // quad_perm [1,0,3,2]
    x = dppadd<0x4E>(x);    // quad_perm [2,3,0,1]
    x = dppadd<0x141>(x);   // row_half_mirror
    x = dppadd<0x140>(x);   // row_mirror
    return x;
}

// Barrier with LDS visibility but NO vmcnt drain.
__device__ __forceinline__ void barrier_lgkm() {
    asm volatile("s_waitcnt lgkmcnt(0)" ::: "memory");
    __builtin_amdgcn_s_barrier();
    asm volatile("" ::: "memory");
}

// ---- prep: cast weights to f16, bsum = b_ih + b_hh ----
__global__ void prep_weights(const float* __restrict__ Wih, const float* __restrict__ Whh,
                             const float* __restrict__ bih, const float* __restrict__ bhh,
                             half_t* __restrict__ WihH, half_t* __restrict__ WhhH,
                             float* __restrict__ bsum)
{
    const int idx = blockIdx.x * 256 + threadIdx.x;
    if (idx < NG * HH) WihH[idx] = (half_t)Wih[idx];
    if (idx < NG * HD) WhhH[idx] = (half_t)Whh[idx];
    if (idx < NG)      bsum[idx] = bih[idx] + bhh[idx];
}

// launch_bounds(512,4): 128 unified VGPR/AGPR per lane. (512,6) spilled the
// fragment set to scratch (round-2: +850 MB HBM). Do not raise waves/EU.
//
// Write strategy (round-6 lesson): in-kernel bulk zeroing pinned every variant
// at ~1.1 TB/s (= ~125 us floor); the driver's memset blit does the same 134 MB
// in ~22 us. So the bulk zeros live in hipMemsetAsync and this kernel writes
// ONLY the <=3 value-carrying 16B chunks per live row (~3 MB total).
__global__ __launch_bounds__(512, 4) void span_lstm_mfma(
    const float* __restrict__ feats, const half_t* __restrict__ WihH,
    const half_t* __restrict__ WhhH, const float* __restrict__ bsum,
    const float* __restrict__ W_tri, const float* __restrict__ b_tri,
    const int* __restrict__ lens, float* __restrict__ out)
{
    __shared__ __align__(16) half_t sFeatb[20 * FP];
    __shared__ __align__(16) float  sXG[20 * XP];
    __shared__ __align__(16) half_t sHb[2][16 * HBP];
    __shared__ __align__(16) float  sE[4][16 * EP];   // [ts][s*EP + wv*2 + tag]

    float* sVal = (float*)sFeatb;   // [16][4][2]; live only after the t-loop

    const int tid = threadIdx.x;
    const int b  = blockIdx.x >> 5;
    const int i0 = (blockIdx.x & 31) * TI;
    const int lens_b = lens[b];

    // ---- dead-block: all spans masked, memset already zeroed the slice ----
    if (i0 >= lens_b) return;

    float* ob = out + ((size_t)b * LL + i0) * (LL * 2);

    const int lane = tid & 63, wv = tid >> 6;   // 8 waves
    const int lm = lane & 15;                   // m / n within 16-tile (DPP row-local)
    const int lq = lane >> 4;                   // quad
    const int jw = wv * 16;                     // this wave's hidden-column slice

    // ---- stage feats window (20 rows) as f16 ----
    for (int idx = tid; idx < 20 * 64; idx += 512) {
        const int p  = idx >> 6;
        const int k4 = (idx & 63) << 2;
        const int gp = i0 + p;
        float4 v = make_float4(0.f, 0.f, 0.f, 0.f);
        if (gp < LL) v = *(const float4*)(feats + ((size_t)b * LL + gp) * HH + k4);
        half4 hv = {(half_t)v.x, (half_t)v.y, (half_t)v.z, (half_t)v.w};
        *(half4*)(&sFeatb[p * FP + k4]) = hv;
    }
    __syncthreads();

    // ---- phase 1: wave computes XG only for ITS gate columns (4 ta x 16 cols) ----
    // sXG is wave-private -> no barrier needed before the t-loop.
    {
        half8 afr[2][8];
        #pragma unroll
        for (int mt = 0; mt < 2; ++mt)
            #pragma unroll
            for (int kf = 0; kf < 8; ++kf)
                afr[mt][kf] = *(const half8*)(&sFeatb[(16 * mt + lm) * FP + kf * 32 + lq * 8]);

        #pragma unroll
        for (int ta = 0; ta < 4; ++ta) {
            const int gb = ta * HD + jw;
            const float bs = bsum[gb + lm];
            f32x4 acc0 = {0.f, 0.f, 0.f, 0.f}, acc1 = {0.f, 0.f, 0.f, 0.f};
            #pragma unroll
            for (int kf = 0; kf < 8; ++kf) {
                const half8 bfr = *(const half8*)(WihH + (size_t)(gb + lm) * HH + kf * 32 + lq * 8);
                acc0 = MFMA16(afr[0][kf], bfr, acc0);
                acc1 = MFMA16(afr[1][kf], bfr, acc1);
            }
            #pragma unroll
            for (int r = 0; r < 4; ++r)
                sXG[(lq * 4 + r) * XP + gb + lm] = acc0[r] + bs;
            if (lq == 0) {
                #pragma unroll
                for (int r = 0; r < 4; ++r)
                    sXG[(16 + r) * XP + gb + lm] = acc1[r] + bs;
            }
        }
    }

    // ---- Whh B-frags: 4 ta x 4 kf for this wave's 16 columns ----
    half8 bf2[4][4];
    #pragma unroll
    for (int ta = 0; ta < 4; ++ta)
        #pragma unroll
        for (int kf = 0; kf < 4; ++kf)
            bf2[ta][kf] = *(const half8*)(WhhH + (size_t)(ta * HD + jw + lm) * HD
                                          + kf * 32 + lq * 8);
    const float wt0 = W_tri[jw + lm];
    const float wt1 = W_tri[HD + jw + lm];
    const float bt0 = b_tri[0], bt1 = b_tri[1];

    float cc4[4] = {0.f, 0.f, 0.f, 0.f};
    float hhA[4][4];   // all 4 steps' h in f32 regs -> emission outside the loop

    // ---- recurrence: minimal barrier-locked body; raw barriers (no vmcnt drain) ----
    #pragma unroll
    for (int t = 0; t < 4; ++t) {
        float accg[4][4];
        if (t > 0) {
            half8 ah[4];
            #pragma unroll
            for (int kf = 0; kf < 4; ++kf)
                ah[kf] = *(const half8*)(&sHb[(t - 1) & 1][lm * HBP + kf * 32 + lq * 8]);
            #pragma unroll
            for (int ta = 0; ta < 4; ++ta) {
                f32x4 a = {0.f, 0.f, 0.f, 0.f};
                #pragma unroll
                for (int kf = 0; kf < 4; ++kf)
                    a = MFMA16(ah[kf], bf2[ta][kf], a);
                #pragma unroll
                for (int r = 0; r < 4; ++r) accg[ta][r] = a[r];
            }
        } else {
            #pragma unroll
            for (int ta = 0; ta < 4; ++ta)
                #pragma unroll
                for (int r = 0; r < 4; ++r) accg[ta][r] = 0.f;
        }
        #pragma unroll
        for (int ta = 0; ta < 4; ++ta)
            #pragma unroll
            for (int r = 0; r < 4; ++r)
                accg[ta][r] += sXG[(lq * 4 + r + t) * XP + ta * HD + jw + lm];

        #pragma unroll
        for (int r = 0; r < 4; ++r) {
            const float ig = sigm(accg[0][r]);
            const float fg = sigm(accg[1][r]);
            const float gg = tanhf_(accg[2][r]);
            const float og = sigm(accg[3][r]);
            cc4[r] = fg * cc4[r] + ig * gg;
            hhA[t][r] = og * tanhf_(cc4[r]);
        }

        if (t < 3) {
            #pragma unroll
            for (int r = 0; r < 4; ++r)
                sHb[t & 1][(lq * 4 + r) * HBP + jw + lm] = (half_t)hhA[t][r];
            barrier_lgkm();
        }
    }

    // ---- emission: DPP row-sums, f32-exact, outside the barrier cadence ----
    #pragma unroll
    for (int ts = 0; ts < 4; ++ts)
        #pragma unroll
        for (int r = 0; r < 4; ++r) {
            float e0 = row16_sum(hhA[ts][r] * wt0);
            float e1 = row16_sum(hhA[ts][r] * wt1);
            if (lm == 0) {
                float2 v = make_float2(e0, e1);
                *(float2*)&sE[ts][(lq * 4 + r) * EP + wv * 2] = v;
            }
        }
    barrier_lgkm();   // sE visible

    // ---- finalize: value per (span-row es, width w, tag) into sVal ----
    if (tid < 128) {
        const int es = tid & 15, tag = (tid >> 4) & 1, w = (tid >> 5) + 1;
        const int i = i0 + es;
        const int rem = lens_b - i;
        float e = 0.f;
        if (rem > 0 && (i + w - 1) < LL) {
            const int ts = (rem < w ? rem : w) - 1;   // selected step (0-based)
            e = tag ? bt1 : bt0;
            #pragma unroll
            for (int k = 0; k < 8; ++k) e += sE[ts][es * EP + k * 2 + tag];
        }
        sVal[(es * 4 + (w - 1)) * 2 + tag] = e;
    }
    barrier_lgkm();   // sVal visible

    // ---- sparse value write: <=3 16B chunks per live row. The bulk zeros
    // were laid down by hipMemsetAsync (same stream, ordered before us). ----
    if (tid < 48) {
        const int es = tid & 15, m = tid >> 4;   // m in 0..2
        const int i = i0 + es;
        if (i < lens_b) {
            const int chi = ((i + 3 < LL) ? (i + 3) : (LL - 1)) >> 1;
            const int c = (i >> 1) + m;
            if (c <= chi) {
                const int j0 = 2 * c;
                f32x4 v = {0.f, 0.f, 0.f, 0.f};
                const int w0 = j0 - i + 1;
                if ((unsigned)(w0 - 1) < 4u) {
                    v.x = sVal[(es * 4 + (w0 - 1)) * 2 + 0];
                    v.y = sVal[(es * 4 + (w0 - 1)) * 2 + 1];
                }
                const int w1 = w0 + 1;
                if ((unsigned)(w1 - 1) < 4u) {
                    v.z = sVal[(es * 4 + (w1 - 1)) * 2 + 0];
                    v.w = sVal[(es * 4 + (w1 - 1)) * 2 + 1];
                }
                *(f32x4*)(ob + ((size_t)es * 256 + c) * 4) = v;
            }
        }
    }
}

extern "C" void kernel_launch(void* const* d_in, const int* in_sizes, int n_in,
                              void* d_out, int out_size, void* d_ws, size_t ws_size,
                              hipStream_t stream)
{
    const float* feats = (const float*)d_in[0];
    const float* W_ih  = (const float*)d_in[1];
    const float* W_hh  = (const float*)d_in[2];
    const float* b_ih  = (const float*)d_in[3];
    const float* b_hh  = (const float*)d_in[4];
    const float* W_tri = (const float*)d_in[5];
    const float* b_tri = (const float*)d_in[6];
    const int*   lens  = (const int*)d_in[7];
    float* out = (float*)d_out;

    // Bulk zeros via the driver blit (~6 TB/s; in-kernel streams cap at ~1.1).
    hipMemsetAsync(out, 0, (size_t)out_size * sizeof(float), stream);

    // ws layout: WihH (256 KB) | WhhH (128 KB) | bsum (2 KB)
    half_t* WihH = (half_t*)d_ws;
    half_t* WhhH = WihH + (size_t)NG * HH;
    float*  bsum = (float*)(WhhH + (size_t)NG * HD);

    prep_weights<<<(NG * HH + 255) / 256, 256, 0, stream>>>(W_ih, W_hh, b_ih, b_hh,
                                                            WihH, WhhH, bsum);
    span_lstm_mfma<<<NB * (LL / TI), 512, 0, stream>>>(feats, WihH, WhhH, bsum,
                                                       W_tri, b_tri, lens, out);
}

// Round 8
// 252.998 us; speedup vs baseline: 1.0517x; 1.0200x over previous
//
#include <hip/hip_runtime.h>
#include <cstddef>

#define NB 64
#define LL 512
#define HH 256
#define HD 128
#define NG 512
#define TI 16

typedef _Float16 half_t;
typedef _Float16 half8 __attribute__((ext_vector_type(8)));
typedef _Float16 half4 __attribute__((ext_vector_type(4)));
typedef float f32x4 __attribute__((ext_vector_type(4)));

#define MFMA16(a, b, c) __builtin_amdgcn_mfma_f32_16x16x32_f16((a), (b), (c), 0, 0, 0)

// LDS pitches (<=2-way bank aliasing, free on CDNA4)
#define FP 264   // sFeatb pitch (f16)
#define XP 518   // sXG pitch (f32)
#define HBP 136  // sHb pitch (f16)
#define EP 17    // sE inner pitch (f32)

// fast gates: v_rcp_f32 (~1 ulp) instead of full-precision divide.
__device__ __forceinline__ float sigm(float x)  { return __builtin_amdgcn_rcpf(1.0f + __expf(-x)); }
__device__ __forceinline__ float tanhf_(float x){ return 2.0f * __builtin_amdgcn_rcpf(1.0f + __expf(-2.0f * x)) - 1.0f; }

// 16-lane (DPP-row) sum on the VALU pipe: no DS ops.
template <int CTRL>
__device__ __forceinline__ float dppadd(float x) {
    int v = __builtin_amdgcn_update_dpp(0, __float_as_int(x), CTRL, 0xF, 0xF, true);
    return x + __int_as_float(v);
}
__device__ __forceinline__ float row16_sum(float x) {
    x = dppadd<0xB1>(x);    // quad_perm [1,0,3,2]
    x = dppadd<0x4E>(x);    // quad_perm [2,3,0,1]
    x = dppadd<0x141>(x);   // row_half_mirror
    x = dppadd<0x140>(x);   // row_mirror
    return x;
}

// Barrier with LDS visibility but NO vmcnt drain.
__device__ __forceinline__ void barrier_lgkm() {
    asm volatile("s_waitcnt lgkmcnt(0)" ::: "memory");
    __builtin_amdgcn_s_barrier();
    asm volatile("" ::: "memory");
}

// ---- prep: cast weights to f16, bsum = b_ih + b_hh ----
__global__ void prep_weights(const float* __restrict__ Wih, const float* __restrict__ Whh,
                             const float* __restrict__ bih, const float* __restrict__ bhh,
                             half_t* __restrict__ WihH, half_t* __restrict__ WhhH,
                             float* __restrict__ bsum)
{
    const int idx = blockIdx.x * 256 + threadIdx.x;
    if (idx < NG * HH) WihH[idx] = (half_t)Wih[idx];
    if (idx < NG * HD) WhhH[idx] = (half_t)Whh[idx];
    if (idx < NG)      bsum[idx] = bih[idx] + bhh[idx];
}

// BATCH-PAIR kernel (round-8): one block = batches (2q, 2q+1) at tile i0.
// Halves live-block count (live iff i0 < max(l0,l1)), doubles per-block ILP
// (two independent b0/b1 chains fill each latency slot), packs both batches'
// overflow rows into one shared phase-1 M-tile (128->96 MFMA).
// LDS ~123 KB -> 1 block/CU -> launch_bounds(512,2) -> 256-VGPR budget
// (t-loop working set ~190 regs: no spill cliff possible).
__global__ __launch_bounds__(512, 2) void span_lstm_mfma(
    const float* __restrict__ feats, const half_t* __restrict__ WihH,
    const half_t* __restrict__ WhhH, const float* __restrict__ bsum,
    const float* __restrict__ W_tri, const float* __restrict__ b_tri,
    const int* __restrict__ lens, float* __restrict__ out)
{
    // 21120 + 78736 + 17408 + 8704 = 125,968 B
    __shared__ __align__(16) half_t sFeatb[40 * FP];        // rows: bb*20 + p
    __shared__ __align__(16) float  sXG[2][19 * XP];        // per batch, rows 0..18
    __shared__ __align__(16) half_t sHb[2][32 * HBP];       // [buf][bb*16 + s]
    __shared__ __align__(16) float  sE[4][32 * EP];         // [ts][(bb*16+s)*EP + wv*2+tag]

    float* sVal = (float*)sFeatb;   // [2][16][4][2]; live only after the t-loop

    const int tid = threadIdx.x;
    const int it = blockIdx.x >> 5;          // tile-major grid: live blocks first
    const int q  = blockIdx.x & 31;
    const int i0 = it * TI;
    const int b0 = 2 * q, b1 = 2 * q + 1;
    const int l0 = lens[b0], l1 = lens[b1];
    const int lmax = l0 > l1 ? l0 : l1;
    if (i0 >= lmax) return;                  // both batches dead here

    const int lane = tid & 63, wv = tid >> 6;   // 8 waves
    const int lm = lane & 15;
    const int lq = lane >> 4;
    const int jw = wv * 16;
    const int gcol = jw + lm;                // hidden-col / gate-col within slice

    // ---- stage feats windows for BOTH batches (40 rows) as f16 ----
    for (int idx = tid; idx < 40 * 64; idx += 512) {
        const int p  = idx >> 6;             // 0..39
        const int k4 = (idx & 63) << 2;
        const int bb = (p >= 20);
        const int pr = p - bb * 20;
        const int gp = i0 + pr;
        float4 v = make_float4(0.f, 0.f, 0.f, 0.f);
        if (gp < LL) v = *(const float4*)(feats + ((size_t)(2 * q + bb) * LL + gp) * HH + k4);
        half4 hv = {(half_t)v.x, (half_t)v.y, (half_t)v.z, (half_t)v.w};
        *(half4*)(&sFeatb[p * FP + k4]) = hv;
    }
    __syncthreads();

    // ---- phase 1: 3 M-tiles (b0 s0-15 | b1 s0-15 | b0 s16-18 + b1 s16-18), kf-outer ----
    // sXG stays wave-private (each wave writes/reads only its gate cols) -> no barrier.
    {
        float bs[4];
        #pragma unroll
        for (int ta = 0; ta < 4; ++ta) bs[ta] = bsum[ta * HD + gcol];

        // M-tile 2 packs both batches' overflow rows: A-row 0-3 = b0 s16-19 (sFeat 16-19),
        // A-row 4-7 = b1 s16-19 (sFeat 36-39); rows 8-15 unused (point at valid LDS).
        const int m2row = (lm < 4) ? (16 + lm) : ((lm < 8) ? (32 + lm) : lm);

        f32x4 acc[3][4];
        #pragma unroll
        for (int mt = 0; mt < 3; ++mt)
            #pragma unroll
            for (int ta = 0; ta < 4; ++ta) acc[mt][ta] = (f32x4){0.f, 0.f, 0.f, 0.f};

        #pragma unroll
        for (int kf = 0; kf < 8; ++kf) {
            const half8 a0 = *(const half8*)(&sFeatb[lm * FP        + kf * 32 + lq * 8]);
            const half8 a1 = *(const half8*)(&sFeatb[(20 + lm) * FP + kf * 32 + lq * 8]);
            const half8 a2 = *(const half8*)(&sFeatb[m2row * FP     + kf * 32 + lq * 8]);
            #pragma unroll
            for (int ta = 0; ta < 4; ++ta) {
                const half8 bfr = *(const half8*)(WihH + (size_t)(ta * HD + gcol) * HH + kf * 32 + lq * 8);
                acc[0][ta] = MFMA16(a0, bfr, acc[0][ta]);
                acc[1][ta] = MFMA16(a1, bfr, acc[1][ta]);
                acc[2][ta] = MFMA16(a2, bfr, acc[2][ta]);
            }
        }
        #pragma unroll
        for (int ta = 0; ta < 4; ++ta) {
            const int col = ta * HD + gcol;
            #pragma unroll
            for (int r = 0; r < 4; ++r) {
                sXG[0][(lq * 4 + r) * XP + col] = acc[0][ta][r] + bs[ta];
                sXG[1][(lq * 4 + r) * XP + col] = acc[1][ta][r] + bs[ta];
            }
            if (lq == 0) {   // m2 rows 0-2 -> b0 s16-18
                #pragma unroll
                for (int r = 0; r < 3; ++r)
                    sXG[0][(16 + r) * XP + col] = acc[2][ta][r] + bs[ta];
            }
            if (lq == 1) {   // m2 rows 4-6 -> b1 s16-18
                #pragma unroll
                for (int r = 0; r < 3; ++r)
                    sXG[1][(16 + r) * XP + col] = acc[2][ta][r] + bs[ta];
            }
        }
    }

    // ---- Whh B-frags: 4 ta x 4 kf for this wave's 16 columns ----
    half8 bf2[4][4];
    #pragma unroll
    for (int ta = 0; ta < 4; ++ta)
        #pragma unroll
        for (int kf = 0; kf < 4; ++kf)
            bf2[ta][kf] = *(const half8*)(WhhH + (size_t)(ta * HD + gcol) * HD + kf * 32 + lq * 8);
    const float wt0 = W_tri[gcol];
    const float wt1 = W_tri[HD + gcol];
    const float bt0 = b_tri[0], bt1 = b_tri[1];

    float cc4[2][4] = {{0.f,0.f,0.f,0.f},{0.f,0.f,0.f,0.f}};
    float hhA[4][2][4];   // all steps' h for both batches, f32, in regs

    // ---- recurrence: two independent batch chains per step, raw barriers ----
    #pragma unroll
    for (int t = 0; t < 4; ++t) {
        float accg[2][4][4];
        if (t > 0) {
            half8 ah0[4], ah1[4];
            #pragma unroll
            for (int kf = 0; kf < 4; ++kf) {
                ah0[kf] = *(const half8*)(&sHb[(t - 1) & 1][lm * HBP        + kf * 32 + lq * 8]);
                ah1[kf] = *(const half8*)(&sHb[(t - 1) & 1][(16 + lm) * HBP + kf * 32 + lq * 8]);
            }
            #pragma unroll
            for (int ta = 0; ta < 4; ++ta) {
                f32x4 a0 = {0.f,0.f,0.f,0.f}, a1 = {0.f,0.f,0.f,0.f};
                #pragma unroll
                for (int kf = 0; kf < 4; ++kf) {
                    a0 = MFMA16(ah0[kf], bf2[ta][kf], a0);
                    a1 = MFMA16(ah1[kf], bf2[ta][kf], a1);
                }
                #pragma unroll
                for (int r = 0; r < 4; ++r) { accg[0][ta][r] = a0[r]; accg[1][ta][r] = a1[r]; }
            }
        } else {
            #pragma unroll
            for (int bb = 0; bb < 2; ++bb)
                #pragma unroll
                for (int ta = 0; ta < 4; ++ta)
                    #pragma unroll
                    for (int r = 0; r < 4; ++r) accg[bb][ta][r] = 0.f;
        }
        #pragma unroll
        for (int bb = 0; bb < 2; ++bb)
            #pragma unroll
            for (int ta = 0; ta < 4; ++ta)
                #pragma unroll
                for (int r = 0; r < 4; ++r)
                    accg[bb][ta][r] += sXG[bb][(lq * 4 + r + t) * XP + ta * HD + gcol];

        #pragma unroll
        for (int bb = 0; bb < 2; ++bb)
            #pragma unroll
            for (int r = 0; r < 4; ++r) {
                const float ig = sigm(accg[bb][0][r]);
                const float fg = sigm(accg[bb][1][r]);
                const float gg = tanhf_(accg[bb][2][r]);
                const float og = sigm(accg[bb][3][r]);
                cc4[bb][r] = fg * cc4[bb][r] + ig * gg;
                hhA[t][bb][r] = og * tanhf_(cc4[bb][r]);
            }

        if (t < 3) {
            #pragma unroll
            for (int bb = 0; bb < 2; ++bb)
                #pragma unroll
                for (int r = 0; r < 4; ++r)
                    sHb[t & 1][(bb * 16 + lq * 4 + r) * HBP + gcol] = (half_t)hhA[t][bb][r];
            barrier_lgkm();
        }
    }

    // ---- emission: DPP row-sums over each 16-col slice, f32-exact ----
    #pragma unroll
    for (int ts = 0; ts < 4; ++ts)
        #pragma unroll
        for (int bb = 0; bb < 2; ++bb)
            #pragma unroll
            for (int r = 0; r < 4; ++r) {
                float e0 = row16_sum(hhA[ts][bb][r] * wt0);
                float e1 = row16_sum(hhA[ts][bb][r] * wt1);
                if (lm == 0) {
                    float2 v = make_float2(e0, e1);
                    *(float2*)&sE[ts][(bb * 16 + lq * 4 + r) * EP + wv * 2] = v;
                }
            }
    barrier_lgkm();   // sE visible

    // ---- finalize: (bb, es, tag, w) per thread -> sVal ----
    if (tid < 256) {
        const int es = tid & 15, tag = (tid >> 4) & 1, w = ((tid >> 5) & 3) + 1, bb = tid >> 7;
        const int lb = bb ? l1 : l0;
        const int i = i0 + es;
        const int rem = lb - i;
        float e = 0.f;
        if (rem > 0 && (i + w - 1) < LL) {
            const int ts = (rem < w ? rem : w) - 1;
            e = tag ? bt1 : bt0;
            #pragma unroll
            for (int k = 0; k < 8; ++k) e += sE[ts][(bb * 16 + es) * EP + k * 2 + tag];
        }
        sVal[((bb * 16 + es) * 4 + (w - 1)) * 2 + tag] = e;
    }
    barrier_lgkm();   // sVal visible

    // ---- sparse value write: <=3 16B chunks per live row, both batches ----
    if (tid < 96) {
        const int bb = (tid >= 48);
        const int r2 = tid - bb * 48;
        const int es = r2 & 15, m = r2 >> 4;    // m in 0..2
        const int lb = bb ? l1 : l0;
        const int i = i0 + es;
        if (i < lb) {
            float* obb = out + ((size_t)(2 * q + bb) * LL + i0) * (LL * 2);
            const int chi = ((i + 3 < LL) ? (i + 3) : (LL - 1)) >> 1;
            const int c = (i >> 1) + m;
            if (c <= chi) {
                const int j0 = 2 * c;
                f32x4 v = {0.f, 0.f, 0.f, 0.f};
                const int w0 = j0 - i + 1;
                if ((unsigned)(w0 - 1) < 4u) {
                    v.x = sVal[((bb * 16 + es) * 4 + (w0 - 1)) * 2 + 0];
                    v.y = sVal[((bb * 16 + es) * 4 + (w0 - 1)) * 2 + 1];
                }
                const int w1 = w0 + 1;
                if ((unsigned)(w1 - 1) < 4u) {
                    v.z = sVal[((bb * 16 + es) * 4 + (w1 - 1)) * 2 + 0];
                    v.w = sVal[((bb * 16 + es) * 4 + (w1 - 1)) * 2 + 1];
                }
                *(f32x4*)(obb + ((size_t)es * 256 + c) * 4) = v;
            }
        }
    }
}

extern "C" void kernel_launch(void* const* d_in, const int* in_sizes, int n_in,
                              void* d_out, int out_size, void* d_ws, size_t ws_size,
                              hipStream_t stream)
{
    const float* feats = (const float*)d_in[0];
    const float* W_ih  = (const float*)d_in[1];
    const float* W_hh  = (const float*)d_in[2];
    const float* b_ih  = (const float*)d_in[3];
    const float* b_hh  = (const float*)d_in[4];
    const float* W_tri = (const float*)d_in[5];
    const float* b_tri = (const float*)d_in[6];
    const int*   lens  = (const int*)d_in[7];
    float* out = (float*)d_out;

    // Bulk zeros via the driver blit (~6 TB/s; in-kernel streams cap at ~1.1).
    hipMemsetAsync(out, 0, (size_t)out_size * sizeof(float), stream);

    // ws layout: WihH (256 KB) | WhhH (128 KB) | bsum (2 KB)
    half_t* WihH = (half_t*)d_ws;
    half_t* WhhH = WihH + (size_t)NG * HH;
    float*  bsum = (float*)(WhhH + (size_t)NG * HD);

    prep_weights<<<(NG * HH + 255) / 256, 256, 0, stream>>>(W_ih, W_hh, b_ih, b_hh,
                                                            WihH, WhhH, bsum);
    // tile-major grid: 32 tiles x 32 batch-pairs
    span_lstm_mfma<<<(LL / TI) * (NB / 2), 512, 0, stream>>>(feats, WihH, WhhH, bsum,
                                                             W_tri, b_tri, lens, out);
}